// Round 1
// 892.889 us; speedup vs baseline: 1.0213x; 1.0213x over previous
//
#include <hip/hip_runtime.h>
#include <stdint.h>

typedef __bf16 bf16x8 __attribute__((ext_vector_type(8)));
typedef float  f32x4  __attribute__((ext_vector_type(4)));

#define F_TOT 8192
#define DIM   1024
#define NEXP  8
#define FF    4096
#define CAP   2560

__device__ __forceinline__ float b2f(unsigned short u){
    union { unsigned int u; float f; } c; c.u = ((unsigned int)u) << 16; return c.f;
}
__device__ __forceinline__ unsigned short f2b(float f){
    union { float f; unsigned int u; } c; c.f = f;
    unsigned int r = c.u + 0x7FFFu + ((c.u >> 16) & 1u);
    return (unsigned short)(r >> 16);
}
__device__ __forceinline__ float ldIn(const void* p, size_t i, int isb){
    return isb ? b2f(((const unsigned short*)p)[i]) : ((const float*)p)[i];
}
__device__ __forceinline__ void gl_lds16(const unsigned short* g, unsigned short* l){
    __builtin_amdgcn_global_load_lds(
        (const __attribute__((address_space(1))) unsigned int*)(g),
        (__attribute__((address_space(3))) unsigned int*)(l),
        16, 0, 0);
}

template<int W> __device__ __forceinline__ void waitcnt_vm(){
    if constexpr (W == 8)      asm volatile("s_waitcnt vmcnt(8)" ::: "memory");
    else if constexpr (W == 4) asm volatile("s_waitcnt vmcnt(4)" ::: "memory");
    else                       asm volatile("s_waitcnt vmcnt(0)" ::: "memory");
}

// ---------------- detect: bf16 vs fp32 inputs (write flag: 1=bf16) ----------
__global__ void detect_kernel(const unsigned short* __restrict__ x, int* __restrict__ flag){
    __shared__ int cnt;
    if (threadIdx.x == 0) cnt = 0;
    __syncthreads();
    unsigned short s = x[threadIdx.x];
    int e = s & 0x7F80;
    if (e >= 0x3000 && e <= 0x4800) atomicAdd(&cnt, 1);
    __syncthreads();
    if (threadIdx.x == 0) flag[0] = (cnt >= 410) ? 1 : 0;
}

// ---------------- gating ----------------------------------------------------
__global__ void gating_kernel(const void* __restrict__ x,
                              const void* __restrict__ Wg, const void* __restrict__ bg,
                              const void* __restrict__ Wn, const void* __restrict__ bn,
                              const int* __restrict__ flag,
                              float* __restrict__ logits, float* __restrict__ nlogits)
{
    int tid = blockIdx.x * blockDim.x + threadIdx.x;
    int t = tid >> 4, o = tid & 15;
    int col = o & 7;
    int isb = flag[0];
    const void* W = (o < 8) ? Wg : Wn;
    float acc = 0.f;
    if (isb){
        const unsigned short* xr = (const unsigned short*)x + (size_t)t * DIM;
        const unsigned short* w  = (const unsigned short*)W;
        #pragma unroll 8
        for (int d = 0; d < DIM; d++) acc = fmaf(b2f(xr[d]), b2f(w[d * 8 + col]), acc);
    } else {
        const float* xr = (const float*)x + (size_t)t * DIM;
        const float* w  = (const float*)W;
        #pragma unroll 8
        for (int d = 0; d < DIM; d++) acc = fmaf(xr[d], w[d * 8 + col], acc);
    }
    acc += ldIn((o < 8) ? bg : bn, col, isb);
    ((o < 8) ? logits : nlogits)[t * 8 + col] = acc;
}

// ---------------- route -----------------------------------------------------
__global__ void route_kernel(const float* __restrict__ logits,
                             const float* __restrict__ nlogits,
                             const void* __restrict__ noise,
                             const int* __restrict__ flag,
                             int* __restrict__ topi, float* __restrict__ gates)
{
    int t = blockIdx.x * blockDim.x + threadIdx.x;
    int isb = flag[0];
    float ny[8];
    #pragma unroll
    for (int e = 0; e < 8; e++){
        float nl = nlogits[t * 8 + e];
        float sp = fmaxf(nl, 0.f) + log1pf(expf(-fabsf(nl)));
        ny[e] = logits[t * 8 + e] + ldIn(noise, (size_t)t * 8 + e, isb) * sp;
    }
    int i0 = 0; float v0 = ny[0];
    #pragma unroll
    for (int e = 1; e < 8; e++) if (ny[e] > v0){ v0 = ny[e]; i0 = e; }
    int i1 = -1; float v1 = -3.4e38f;
    #pragma unroll
    for (int e = 0; e < 8; e++) if (e != i0 && ny[e] > v1){ v1 = ny[e]; i1 = e; }
    float e1 = expf(v1 - v0);
    float den = 1.f + e1;
    topi[t * 2]      = i0;  topi[t * 2 + 1] = i1;
    gates[t * 2]     = 1.f / den;
    gates[t * 2 + 1] = e1 / den;
}

// ---------------- scan: dispatch[e][pos]=t, slotf[t][k]=e*CAP+pos, cnt[e] ---
__global__ __launch_bounds__(1024)
void scan_kernel(const int* __restrict__ topi,
                 int* __restrict__ dispatch, int* __restrict__ slotf,
                 int* __restrict__ cntbuf)
{
    int e = blockIdx.x;
    int tid = threadIdx.x;
    for (int c = tid; c < CAP; c += 1024) dispatch[e * CAP + c] = F_TOT;
    int base = tid * 8;
    int kk[8]; int cnt = 0;
    #pragma unroll
    for (int j = 0; j < 8; j++){
        int t = base + j;
        int k = (topi[t * 2] == e) ? 0 : ((topi[t * 2 + 1] == e) ? 1 : -1);
        kk[j] = k; if (k >= 0) cnt++;
    }
    __shared__ int s[1024];
    s[tid] = cnt; __syncthreads();
    for (int off = 1; off < 1024; off <<= 1){
        int v = (tid >= off) ? s[tid - off] : 0;
        __syncthreads();
        s[tid] += v;
        __syncthreads();
    }
    if (tid == 1023) cntbuf[e] = s[1023];
    int pos = s[tid] - cnt;
    #pragma unroll
    for (int j = 0; j < 8; j++){
        if (kk[j] >= 0){
            int t = base + j;
            if (pos < CAP){
                dispatch[e * CAP + pos] = t;
                slotf[t * 2 + kk[j]] = e * CAP + pos;
            } else {
                slotf[t * 2 + kk[j]] = -1;     // dropped (over capacity)
            }
            pos++;
        }
    }
}

// ---------------- convert x -> bf16 -----------------------------------------
__global__ void convx_kernel(const void* __restrict__ x, const int* __restrict__ flag,
                             unsigned short* __restrict__ xb)
{
    size_t i = ((size_t)blockIdx.x * blockDim.x + threadIdx.x) * 8;
    if (flag[0]){
        ushort4 a = *(const ushort4*)((const unsigned short*)x + i);
        ushort4 b = *(const ushort4*)((const unsigned short*)x + i + 4);
        *(ushort4*)(xb + i) = a;  *(ushort4*)(xb + i + 4) = b;
    } else {
        float4 a = *(const float4*)((const float*)x + i);
        float4 b = *(const float4*)((const float*)x + i + 4);
        ushort4 lo, hi;
        lo.x = f2b(a.x); lo.y = f2b(a.y); lo.z = f2b(a.z); lo.w = f2b(a.w);
        hi.x = f2b(b.x); hi.y = f2b(b.y); hi.z = f2b(b.z); hi.w = f2b(b.w);
        *(ushort4*)(xb + i) = lo; *(ushort4*)(xb + i + 4) = hi;
    }
}

// ---------------- transpose (dual-dtype in, bf16 out) -----------------------
__global__ void transpose_kernel(const void* __restrict__ in,
                                 unsigned short* __restrict__ out,
                                 const int* __restrict__ flag,
                                 int R, int C, int eBase)
{
    __shared__ unsigned short tile[64][68];
    const size_t mi = (size_t)(eBase + blockIdx.z) * R * C;
    const size_t mo = (size_t)blockIdx.z * R * C;
    int c0 = blockIdx.x * 64, r0 = blockIdx.y * 64;
    int t = threadIdx.x;
    int rr = t >> 4, cc = (t & 15) * 4;
    int isb = flag[0];
    #pragma unroll
    for (int i = 0; i < 4; i++){
        int r = rr + i * 16;
        size_t idx = mi + (size_t)(r0 + r) * C + c0 + cc;
        if (isb){
            ushort4 v = *(const ushort4*)((const unsigned short*)in + idx);
            *(ushort4*)&tile[r][cc] = v;
        } else {
            float4 v = *(const float4*)((const float*)in + idx);
            ushort4 u; u.x = f2b(v.x); u.y = f2b(v.y); u.z = f2b(v.z); u.w = f2b(v.w);
            *(ushort4*)&tile[r][cc] = u;
        }
    }
    __syncthreads();
    #pragma unroll
    for (int i = 0; i < 4; i++){
        int c = rr + i * 16;
        ushort4 v;
        v.x = tile[cc + 0][c]; v.y = tile[cc + 1][c];
        v.z = tile[cc + 2][c]; v.w = tile[cc + 3][c];
        *(ushort4*)(out + mo + (size_t)(c0 + c) * R + r0 + cc) = v;
    }
}

// ---------------- pipelined 256x256 FFN GEMM --------------------------------
// BM=BN=256, BK=32, 8 waves (2M x 4N), 4-deep LDS K-tile ring (128 KiB),
// counted vmcnt(8) (never 0 in steady state), raw s_barrier (no drain),
// XOR bank swizzle: LDS dest linear, global SOURCE inverse-permuted,
// read addr ^= ((row&7)<<4)  -> 2-way-only bank aliasing (free).
// ISF0: gather rows via dispatch, gelu epilogue, out indexed by expert-local.

#define STAGE_A(kt) { \
    unsigned short* d_ = smem + (((kt)&3)<<14) + (tid<<3); \
    gl_lds16(aS0 + (size_t)(kt)*32, d_); \
    gl_lds16(aS1 + (size_t)(kt)*32, d_ + 4096); }

#define STAGE_B(kt) { \
    unsigned short* d_ = smem + (((kt)&3)<<14) + 8192 + (tid<<3); \
    gl_lds16(bS0 + (size_t)(kt)*32, d_); \
    gl_lds16(bS1 + (size_t)(kt)*32, d_ + 4096); }

#define KTILE(T, DS, W) { \
    waitcnt_vm<W>(); \
    __builtin_amdgcn_s_barrier(); \
    asm volatile("" ::: "memory"); \
    const char* bufc = (const char*)smem + (((size_t)((T)&3))<<15); \
    bf16x8 bfv[4], afv[4]; \
    _Pragma("unroll") \
    for (int j = 0; j < 4; j++){ \
        int r_ = rB0 + j*16 + l16; \
        bfv[j] = *(const bf16x8*)(bufc + boff + (((r_<<6)|(quad<<4)) ^ sx)); \
    } \
    _Pragma("unroll") \
    for (int i = 0; i < 4; i++){ \
        int r_ = i*16 + l16; \
        afv[i] = *(const bf16x8*)(bufc + aoff + (((r_<<6)|(quad<<4)) ^ sx)); \
    } \
    if (DS){ STAGE_A((T)+3); } \
    __builtin_amdgcn_s_setprio(1); \
    _Pragma("unroll") \
    for (int i = 0; i < 4; i++) \
        _Pragma("unroll") \
        for (int j = 0; j < 4; j++) \
            acc[i][j] = __builtin_amdgcn_mfma_f32_16x16x32_bf16(afv[i], bfv[j], acc[i][j], 0, 0, 0); \
    __builtin_amdgcn_s_setprio(0); \
    __builtin_amdgcn_s_barrier(); \
    _Pragma("unroll") \
    for (int i = 0; i < 4; i++){ \
        int r_ = (i+4)*16 + l16; \
        afv[i] = *(const bf16x8*)(bufc + aoff + (((r_<<6)|(quad<<4)) ^ sx)); \
    } \
    if (DS){ STAGE_B((T)+3); } \
    __builtin_amdgcn_s_setprio(1); \
    _Pragma("unroll") \
    for (int i = 0; i < 4; i++) \
        _Pragma("unroll") \
        for (int j = 0; j < 4; j++) \
            acc[i+4][j] = __builtin_amdgcn_mfma_f32_16x16x32_bf16(afv[i], bfv[j], acc[i+4][j], 0, 0, 0); \
    __builtin_amdgcn_s_setprio(0); \
}

template<int KT, int NT, bool ISF0>
__global__ __launch_bounds__(512, 2)
void ffn_pipe_kernel(const unsigned short* __restrict__ Ain,   // xb or h
                     const unsigned short* __restrict__ Wt,    // [4][NT][KT] bf16
                     const void* __restrict__ bias,
                     const int* __restrict__ flag,
                     unsigned short* __restrict__ Out,         // h or eo
                     const int* __restrict__ dispatch,
                     const int* __restrict__ cnt,
                     int eBase)
{
    constexpr int NTN = NT / 256;
    constexpr int NK  = KT / 32;
    const int el = blockIdx.y, eg = el + eBase;
    const int nt = blockIdx.x % NTN;
    const int mt = blockIdx.x / NTN;
    const int m0 = mt * 256, n0 = nt * 256;
    if (m0 >= cnt[eg]) return;          // whole m-tile past expert row count

    const int tid = threadIdx.x, lane = tid & 63, wave = tid >> 6;
    const int wm = wave >> 2, wn = wave & 3;          // 2M x 4N wave grid
    const int quad = lane >> 4, l16 = lane & 15;
    const int sx = (l16 & 7) << 4;                    // read-side XOR swizzle
    const int aoff = wm * 8192;                       // byte base of A half
    const int boff = 16384 + (wn >> 1) * 8192;        // byte base of B half
    const int rB0  = (wn & 1) * 64;                   // row base inside B half

    __shared__ __align__(16) unsigned short smem[65536];   // 128 KiB, 4 K-tiles

    // ---- staging source: invert P = L ^ ((L>>2)&7) to find logical unit ----
    const int P  = tid;
    const int q2 = ((P >> 2) ^ (P >> 4)) & 1;
    const int q1 = ((P >> 1) ^ (P >> 3)) & 1;
    const int q0 = (P ^ (P >> 2) ^ (P >> 4)) & 1;
    const int L  = (P & ~7) | (q2 << 2) | (q1 << 1) | q0;
    const int rs = L >> 2;          // 0..127 row within half-tile
    const int cs = (L & 3) * 8;     // element offset within 32-wide k chunk

    const unsigned short* aS0;
    const unsigned short* aS1;
    if (ISF0){
        int t0 = dispatch[eg * CAP + m0 + rs];
        int t1 = dispatch[eg * CAP + m0 + 128 + rs];
        if (((unsigned)t0) >= (unsigned)F_TOT) t0 = 0;
        if (((unsigned)t1) >= (unsigned)F_TOT) t1 = 0;
        aS0 = Ain + (size_t)t0 * KT + cs;
        aS1 = Ain + (size_t)t1 * KT + cs;
    } else {
        aS0 = Ain + ((size_t)(el * CAP + m0 + rs)) * KT + cs;
        aS1 = Ain + ((size_t)(el * CAP + m0 + 128 + rs)) * KT + cs;
    }
    const unsigned short* bE  = Wt + (size_t)el * NT * KT;
    const unsigned short* bS0 = bE + (size_t)(n0 + rs) * KT + cs;
    const unsigned short* bS1 = bE + (size_t)(n0 + 128 + rs) * KT + cs;

    f32x4 acc[8][4] = {};

    // prologue: stage K-tiles 0,1,2 (12 loads/thread, in order)
    STAGE_A(0); STAGE_B(0);
    STAGE_A(1); STAGE_B(1);
    STAGE_A(2); STAGE_B(2);

    for (int t = 0; t < NK - 3; ++t){ KTILE(t, 1, 8); }
    KTILE(NK - 3, 0, 8);
    KTILE(NK - 2, 0, 4);
    KTILE(NK - 1, 0, 0);

    // ---- epilogue: bias (+gelu for ffn0), bf16 store ----
    const int isb = flag[0];
    const int rBase = m0 + wm * 128 + quad * 4;
    const int cBase = n0 + wn * 64 + l16;
    float bv[4];
    #pragma unroll
    for (int j = 0; j < 4; j++) bv[j] = ldIn(bias, (size_t)eg * NT + cBase + j * 16, isb);
    const int oe = ISF0 ? el : eg;
    #pragma unroll
    for (int i = 0; i < 8; i++)
        #pragma unroll
        for (int j = 0; j < 4; j++)
            #pragma unroll
            for (int r = 0; r < 4; r++){
                int row = rBase + i * 16 + r;
                float v = acc[i][j][r] + bv[j];
                if (ISF0) v = 0.5f * v * (1.0f + erff(v * 0.70710678118654752f));
                Out[((size_t)(oe * CAP + row)) * NT + cBase + j * 16] = f2b(v);
            }
}

// ---------------- combine: out[t] = g0*eo[s0] + g1*eo[s1] -------------------
__global__ void combine_kernel(const unsigned short* __restrict__ eo,
                               const int* __restrict__ slotf,
                               const float* __restrict__ gates,
                               const int* __restrict__ flag,
                               void* __restrict__ out)
{
    int t = blockIdx.x;
    int d = threadIdx.x * 4;
    int s0 = slotf[t * 2], s1 = slotf[t * 2 + 1];
    float g0 = gates[t * 2], g1 = gates[t * 2 + 1];
    float a0 = 0.f, a1 = 0.f, a2 = 0.f, a3 = 0.f;
    if (((unsigned)s0) < (unsigned)(NEXP * CAP)){
        ushort4 a = *(const ushort4*)(eo + (size_t)s0 * DIM + d);
        a0 += g0 * b2f(a.x); a1 += g0 * b2f(a.y);
        a2 += g0 * b2f(a.z); a3 += g0 * b2f(a.w);
    }
    if (((unsigned)s1) < (unsigned)(NEXP * CAP)){
        ushort4 a = *(const ushort4*)(eo + (size_t)s1 * DIM + d);
        a0 += g1 * b2f(a.x); a1 += g1 * b2f(a.y);
        a2 += g1 * b2f(a.z); a3 += g1 * b2f(a.w);
    }
    if (flag[0]){
        ushort4 o; o.x = f2b(a0); o.y = f2b(a1); o.z = f2b(a2); o.w = f2b(a3);
        *(ushort4*)((unsigned short*)out + (size_t)t * DIM + d) = o;
    } else {
        float4 o; o.x = a0; o.y = a1; o.z = a2; o.w = a3;
        *(float4*)((float*)out + (size_t)t * DIM + d) = o;
    }
}

// ---------------- launch ----------------------------------------------------
extern "C" void kernel_launch(void* const* d_in, const int* in_sizes, int n_in,
                              void* d_out, int out_size, void* d_ws, size_t ws_size,
                              hipStream_t stream)
{
    const void* x     = d_in[0];
    const void* noise = d_in[1];
    const void* Wg    = d_in[2];
    const void* bg    = d_in[3];
    const void* Wn    = d_in[4];
    const void* bn    = d_in[5];
    const void* W1    = d_in[6];
    const void* b1    = d_in[7];
    const void* W2    = d_in[8];
    const void* b2    = d_in[9];
    char* ws = (char*)d_ws;

    float* logits  = (float*)(ws + 0);            // 262144
    float* nlogits = (float*)(ws + 262144);       // 262144
    int*   topi    = (int*)  (ws + 524288);       // 65536
    float* gates   = (float*)(ws + 589824);       // 65536
    int*   disp    = (int*)  (ws + 655360);       // 81920
    int*   slotf   = (int*)  (ws + 737280);       // 65536
    int*   flag    = (int*)  (ws + 802816);       // 4
    int*   cnt     = (int*)  (ws + 803072);       // 32
    unsigned short* xb = (unsigned short*)(ws + 1048576);    // 16,777,216
    unsigned short* Wt = (unsigned short*)(ws + 17825792);   // 33,554,432 (4 experts)
    unsigned short* h  = (unsigned short*)(ws + 51380224);   // 83,886,080 (4 experts)
    unsigned short* eo = (unsigned short*)(ws + 135266304);  // 41,943,040 (8 experts)
    // total 177,209,344 B

    detect_kernel<<<1, 512, 0, stream>>>((const unsigned short*)x, flag);
    gating_kernel<<<512, 256, 0, stream>>>(x, Wg, bg, Wn, bn, flag, logits, nlogits);
    route_kernel<<<32, 256, 0, stream>>>(logits, nlogits, noise, flag, topi, gates);
    scan_kernel<<<8, 1024, 0, stream>>>(topi, disp, slotf, cnt);
    convx_kernel<<<4096, 256, 0, stream>>>(x, flag, xb);

    for (int g = 0; g < 2; g++){
        int eB = g * 4;
        transpose_kernel<<<dim3(64, 16, 4), 256, 0, stream>>>(W1, Wt, flag, DIM, FF, eB);
        ffn_pipe_kernel<DIM, FF, true><<<dim3((FF/256) * (CAP/256), 4), 512, 0, stream>>>(
            xb, Wt, b1, flag, h, disp, cnt, eB);
        transpose_kernel<<<dim3(16, 64, 4), 256, 0, stream>>>(W2, Wt, flag, FF, DIM, eB);
        ffn_pipe_kernel<FF, DIM, false><<<dim3((DIM/256) * (CAP/256), 4), 512, 0, stream>>>(
            h, Wt, b2, flag, eo, disp, cnt, eB);
    }
    combine_kernel<<<F_TOT, 256, 0, stream>>>(eo, slotf, gates, flag, d_out);
}